// Round 6
// baseline (220.953 us; speedup 1.0000x reference)
//
#include <hip/hip_runtime.h>
#include <stdint.h>

typedef uint16_t u16;
typedef uint32_t u32;

#define NS 4096
#define NTOT 8192
#define DIM 512

typedef __attribute__((ext_vector_type(8))) short bf16x8;
typedef __attribute__((ext_vector_type(4))) float f32x4;

__device__ inline u16 f2bf(float f) {
    u32 u = __float_as_uint(f);
    return (u16)((u + 0x7fffu + ((u >> 16) & 1u)) >> 16);
}

// Fragment-major Tb: fragment (rb, kt) = 16 rows x 32 cols bf16, contiguous 1 KiB at
// Tb + (rb*16+kt)*512 (u16). Interior lane-linear for mfma_f32_16x16x32_bf16: u16
// offset (fq*16+fr)*8 holds row rb*16+fr, k-octet fq. MFMA fragments load DIRECTLY
// from global with one coalesced dwordx4 per lane (no LDS staging needed).

// k_prep: 256 blocks x 256 thr; block = 32 rows (frag-rows rb=2b,2b+1).
// Wave w handles rows (w&1)*8..+7 of local frag-row (w>>1). LDS transpose ->
// contiguous 1 KiB global stores. Also per-row sumsq and per-block colsums.
__global__ __launch_bounds__(256) void k_prep(const float* __restrict__ src,
                                              const float* __restrict__ tgt,
                                              u16* __restrict__ Tb,
                                              float* __restrict__ sq,
                                              float* __restrict__ cp) {
    __shared__ u16 xb[2][16][520];      // 520 = 512 + 8 u16 pad (1040 B row stride)
    __shared__ float cs_l[4][DIM];
    const int b = blockIdx.x, tid = threadIdx.x;
    const int w = tid >> 6, lane = tid & 63;
    const int rbl = w >> 1;             // local frag-row 0/1
    const int i0 = (w & 1) * 8;

    float cs[8];
#pragma unroll
    for (int e = 0; e < 8; ++e) cs[e] = 0.f;

#pragma unroll
    for (int i = 0; i < 8; ++i) {
        const int fr = i0 + i;
        const int r = b * 32 + rbl * 16 + fr;
        const float* rowp = (r < NS) ? (src + (size_t)r * DIM)
                                     : (tgt + (size_t)(r - NS) * DIM);
        float4 v0 = *(const float4*)(rowp + lane * 8);
        float4 v1 = *(const float4*)(rowp + lane * 8 + 4);
        float vx[8] = {v0.x, v0.y, v0.z, v0.w, v1.x, v1.y, v1.z, v1.w};
        float ss = 0.f;
#pragma unroll
        for (int e = 0; e < 8; ++e) { ss += vx[e] * vx[e]; cs[e] += vx[e]; }
        u32 pk[4];
#pragma unroll
        for (int e = 0; e < 4; ++e)
            pk[e] = (u32)f2bf(vx[2 * e]) | ((u32)f2bf(vx[2 * e + 1]) << 16);
        *(uint4*)&xb[rbl][fr][lane * 8] = make_uint4(pk[0], pk[1], pk[2], pk[3]);
#pragma unroll
        for (int off = 32; off; off >>= 1) ss += __shfl_down(ss, off);
        if (lane == 0) sq[r] = ss;
    }
#pragma unroll
    for (int e = 0; e < 8; ++e) cs_l[w][lane * 8 + e] = cs[e];
    __syncthreads();

    // transpose write: wave w stores frags kt=(w&1)*8+t of frag-row rbl, coalesced.
    const int fq = lane >> 4, frx = lane & 15;
    const int rbg = b * 2 + rbl;
#pragma unroll
    for (int tt = 0; tt < 8; ++tt) {
        const int kt = (w & 1) * 8 + tt;
        uint4 v = *(const uint4*)&xb[rbl][frx][(kt * 4 + fq) * 8];
        *(uint4*)(Tb + (size_t)(rbg * 16 + kt) * 512 + lane * 8) = v;
    }

    float a0 = cs_l[0][tid] + cs_l[1][tid] + cs_l[2][tid] + cs_l[3][tid];
    float a1 = cs_l[0][tid + 256] + cs_l[1][tid + 256] + cs_l[2][tid + 256] + cs_l[3][tid + 256];
    cp[(size_t)b * DIM + tid] = a0;
    cp[(size_t)b * DIM + tid + 256] = a1;
}

// k_band: bandwidth via sum(l2) = 2*N*sum(sq) - 2*||colsum||^2 (reads 544 KB).
// Natural-log scales -1/(bw_i+eps); zeroes accum+counter for k_mmd.
__global__ __launch_bounds__(256) void k_band(const float* __restrict__ sq,
                                              const float* __restrict__ cp,
                                              float* __restrict__ scales,
                                              double* __restrict__ accum,
                                              u32* __restrict__ counter) {
    __shared__ double red[4];
    const int tid = threadIdx.x;
    const int w = tid >> 6, lane = tid & 63;

    double ssq = 0.0;
    for (int i = tid; i < NTOT; i += 256) ssq += (double)sq[i];

    double s2 = 0.0;
#pragma unroll
    for (int cc = 0; cc < 2; ++cc) {
        const int c = tid + cc * 256;
        float a0 = 0.f, a1 = 0.f, a2 = 0.f, a3 = 0.f;
#pragma unroll 8
        for (int b = 0; b < 256; b += 4) {
            a0 += cp[(size_t)(b + 0) * DIM + c];
            a1 += cp[(size_t)(b + 1) * DIM + c];
            a2 += cp[(size_t)(b + 2) * DIM + c];
            a3 += cp[(size_t)(b + 3) * DIM + c];
        }
        double sc = (double)a0 + (double)a1 + (double)a2 + (double)a3;
        s2 += sc * sc;
    }

    auto blkreduce = [&](double v) -> double {
#pragma unroll
        for (int off = 32; off; off >>= 1) v += __shfl_down(v, off);
        __syncthreads();
        if (lane == 0) red[w] = v;
        __syncthreads();
        return red[0] + red[1] + red[2] + red[3];
    };

    double sumsq = blkreduce(ssq);
    double s2t = blkreduce(s2);

    if (tid < 5) {
        const double nn = (double)NTOT;
        double bw = (2.0 * nn * sumsq - 2.0 * s2t) / (nn * nn - nn);
        const double fac[5] = {0.25, 0.5, 1.0, 2.0, 4.0};
        scales[tid] = (float)(-1.0 / (bw * fac[tid] + 1e-8));
    }
    if (tid == 5) *accum = 0.0;
    if (tid == 6) *counter = 0u;
}

// k_mmd: LDS-free gram + kernel-sum. Fragments load straight from fragment-major Tb
// to VGPRs (coalesced dwordx4). No barriers in the K-loop -> pure wave dataflow.
__global__ __launch_bounds__(256, 4) void k_mmd(const u16* __restrict__ Tb,
                                                const float* __restrict__ sq,
                                                const float* __restrict__ scales,
                                                double* __restrict__ accum,
                                                u32* __restrict__ counter,
                                                float* __restrict__ out) {
    __shared__ double red[4];

    // XCD-aware bijective swizzle (2080 = 8*260), then triangular decomposition.
    const int orig = blockIdx.x;
    const int t = (orig & 7) * 260 + (orig >> 3);
    int bi = (int)((sqrtf(8.0f * (float)t + 1.0f) - 1.0f) * 0.5f);
    while ((bi + 1) * (bi + 2) / 2 <= t) ++bi;
    while (bi * (bi + 1) / 2 > t) --bi;
    const int bj = t - bi * (bi + 1) / 2;

    const int tid = threadIdx.x;
    const int wid = tid >> 6, lane = tid & 63;
    const int wr = wid >> 1, wc = wid & 1;
    const int fr = lane & 15, fq = lane >> 4;

    f32x4 acc[4][4];
#pragma unroll
    for (int m = 0; m < 4; ++m)
#pragma unroll
        for (int n = 0; n < 4; ++n) acc[m][n] = (f32x4){0.f, 0.f, 0.f, 0.f};

    const u16* pA[4];
    const u16* pB[4];
#pragma unroll
    for (int m = 0; m < 4; ++m)
        pA[m] = Tb + (size_t)((bi * 8 + wr * 4 + m) * 16) * 512 + lane * 8;
#pragma unroll
    for (int n = 0; n < 4; ++n)
        pB[n] = Tb + (size_t)((bj * 8 + wc * 4 + n) * 16) * 512 + lane * 8;

#pragma unroll
    for (int kt = 0; kt < 16; ++kt) {
        bf16x8 af[4], bfr[4];
#pragma unroll
        for (int m = 0; m < 4; ++m) af[m] = *(const bf16x8*)(pA[m] + kt * 512);
#pragma unroll
        for (int n = 0; n < 4; ++n) bfr[n] = *(const bf16x8*)(pB[n] + kt * 512);
#pragma unroll
        for (int m = 0; m < 4; ++m)
#pragma unroll
            for (int n = 0; n < 4; ++n)
                acc[m][n] = __builtin_amdgcn_mfma_f32_16x16x32_bf16(af[m], bfr[n], acc[m][n], 0, 0, 0);
    }

    // epilogue: l2 -> 5x __expf -> f32 per-thread sum -> f64 block reduce.
    const float c0 = scales[0], c1 = scales[1], c2 = scales[2], c3 = scales[3], c4 = scales[4];
    const int rowA0 = bi * 128, rowB0 = bj * 128;
    float sqc[4];
#pragma unroll
    for (int n = 0; n < 4; ++n) sqc[n] = sq[rowB0 + wc * 64 + n * 16 + fr];

    float facc = 0.f;
#pragma unroll
    for (int m = 0; m < 4; ++m) {
        float4 s4 = *(const float4*)(sq + rowA0 + wr * 64 + m * 16 + fq * 4);
        float sqr[4] = {s4.x, s4.y, s4.z, s4.w};
#pragma unroll
        for (int n = 0; n < 4; ++n) {
#pragma unroll
            for (int r = 0; r < 4; ++r) {
                float g = acc[m][n][r];
                float l2 = fmaxf(sqr[r] + sqc[n] - 2.0f * g, 0.0f);
                facc += __expf(c0 * l2) + __expf(c1 * l2) + __expf(c2 * l2)
                      + __expf(c3 * l2) + __expf(c4 * l2);
            }
        }
    }

    const double wfac = ((bi == bj) ? 1.0 : 2.0) *
                        (((bi < 32) == (bj < 32)) ? 1.0 : -1.0);
    double lacc = (double)facc;
#pragma unroll
    for (int off = 32; off; off >>= 1) lacc += __shfl_down(lacc, off);
    if (lane == 0) red[wid] = lacc;
    __syncthreads();

    if (tid == 0) {
        atomicAdd(accum, (red[0] + red[1] + red[2] + red[3]) * wfac);
        __threadfence();
        u32 done = atomicAdd(counter, 1u);
        if (done == 2079u) {
            double tot = atomicAdd(accum, 0.0);   // device-scope coherent read
            out[0] = (float)(tot / ((double)NS * (double)NS));
        }
    }
}

extern "C" void kernel_launch(void* const* d_in, const int* in_sizes, int n_in,
                              void* d_out, int out_size, void* d_ws, size_t ws_size,
                              hipStream_t stream) {
    const float* src = (const float*)d_in[0];
    const float* tgt = (const float*)d_in[1];
    char* ws = (char*)d_ws;

    const size_t MB8 = 8u * 1024 * 1024;
    u16* Tb       = (u16*)ws;                                 // 8 MiB fragment-major
    float* sq     = (float*)(ws + MB8);                       // 32 KiB
    float* cp     = (float*)(ws + MB8 + 32 * 1024);           // 512 KiB
    float* scales = (float*)(ws + MB8 + 544 * 1024);          // 32 B
    double* accum = (double*)(ws + MB8 + 544 * 1024 + 64);    // 8 B
    u32* counter  = (u32*)(ws + MB8 + 544 * 1024 + 80);       // 4 B

    k_prep<<<256, 256, 0, stream>>>(src, tgt, Tb, sq, cp);
    k_band<<<1, 256, 0, stream>>>(sq, cp, scales, accum, counter);
    k_mmd<<<2080, 256, 0, stream>>>(Tb, sq, scales, accum, counter, (float*)d_out);
}

// Round 7
// 220.045 us; speedup vs baseline: 1.0041x; 1.0041x over previous
//
#include <hip/hip_runtime.h>
#include <stdint.h>

typedef uint16_t u16;
typedef uint32_t u32;

#define NS 4096
#define NTOT 8192
#define DIM 512

typedef __attribute__((ext_vector_type(8))) short bf16x8;
typedef __attribute__((ext_vector_type(4))) float f32x4;

__device__ inline u16 f2bf(float f) {
    u32 u = __float_as_uint(f);
    return (u16)((u + 0x7fffu + ((u >> 16) & 1u)) >> 16);
}

// Fragment-major Tb: fragment (rb, kt) = 16 rows x 32 cols bf16, contiguous 1 KiB at
// Tb + (rb*16+kt)*512 (u16); u16 offset (fq*16+fr)*8 holds row rb*16+fr, k-octet fq.
// MFMA fragments load DIRECTLY from global: one coalesced dwordx4 per lane.

// k_prep: 256 blocks x 256 thr; block = 32 rows. bf16 conversion via LDS transpose
// (contiguous 1 KiB stores), per-row sumsq, per-block colsum partials.
// LAST block (atomic counter) computes bandwidth scales + zeroes accum (fused k_band).
__global__ __launch_bounds__(256) void k_prep(const float* __restrict__ src,
                                              const float* __restrict__ tgt,
                                              u16* __restrict__ Tb,
                                              float* __restrict__ sq,
                                              float* __restrict__ cp,
                                              float* __restrict__ scales,
                                              double* __restrict__ accum,
                                              u32* __restrict__ ctr) {
    __shared__ u16 xb[2][16][520];
    __shared__ float cs_l[4][DIM];
    __shared__ int lastflag;
    __shared__ double red[4];
    const int b = blockIdx.x, tid = threadIdx.x;
    const int w = tid >> 6, lane = tid & 63;
    const int rbl = w >> 1;
    const int i0 = (w & 1) * 8;

    float cs[8];
#pragma unroll
    for (int e = 0; e < 8; ++e) cs[e] = 0.f;

#pragma unroll
    for (int i = 0; i < 8; ++i) {
        const int fr = i0 + i;
        const int r = b * 32 + rbl * 16 + fr;
        const float* rowp = (r < NS) ? (src + (size_t)r * DIM)
                                     : (tgt + (size_t)(r - NS) * DIM);
        float4 v0 = *(const float4*)(rowp + lane * 8);
        float4 v1 = *(const float4*)(rowp + lane * 8 + 4);
        float vx[8] = {v0.x, v0.y, v0.z, v0.w, v1.x, v1.y, v1.z, v1.w};
        float ss = 0.f;
#pragma unroll
        for (int e = 0; e < 8; ++e) { ss += vx[e] * vx[e]; cs[e] += vx[e]; }
        u32 pk[4];
#pragma unroll
        for (int e = 0; e < 4; ++e)
            pk[e] = (u32)f2bf(vx[2 * e]) | ((u32)f2bf(vx[2 * e + 1]) << 16);
        *(uint4*)&xb[rbl][fr][lane * 8] = make_uint4(pk[0], pk[1], pk[2], pk[3]);
#pragma unroll
        for (int off = 32; off; off >>= 1) ss += __shfl_down(ss, off);
        if (lane == 0) sq[r] = ss;
    }
#pragma unroll
    for (int e = 0; e < 8; ++e) cs_l[w][lane * 8 + e] = cs[e];
    __syncthreads();

    // transpose write: wave w stores frags kt=(w&1)*8+tt of frag-row rbl, coalesced.
    const int fq = lane >> 4, frx = lane & 15;
    const int rbg = b * 2 + rbl;
#pragma unroll
    for (int tt = 0; tt < 8; ++tt) {
        const int kt = (w & 1) * 8 + tt;
        uint4 v = *(const uint4*)&xb[rbl][frx][(kt * 4 + fq) * 8];
        *(uint4*)(Tb + (size_t)(rbg * 16 + kt) * 512 + lane * 8) = v;
    }

    float a0 = cs_l[0][tid] + cs_l[1][tid] + cs_l[2][tid] + cs_l[3][tid];
    float a1 = cs_l[0][tid + 256] + cs_l[1][tid + 256] + cs_l[2][tid + 256] + cs_l[3][tid + 256];
    cp[(size_t)b * DIM + tid] = a0;
    cp[(size_t)b * DIM + tid + 256] = a1;

    // ---- fused bandwidth tail: last-done block reduces cp+sq -> scales ----
    __threadfence();                       // release cp/sq/Tb device-scope
    if (tid == 0) lastflag = (atomicAdd(ctr, 1u) == 255u) ? 1 : 0;
    __syncthreads();
    if (!lastflag) return;
    __threadfence();                       // acquire

    double ssq = 0.0;
    for (int i = tid; i < NTOT; i += 256) ssq += (double)sq[i];

    double s2 = 0.0;
#pragma unroll
    for (int cc = 0; cc < 2; ++cc) {
        const int c = tid + cc * 256;
        float b0 = 0.f, b1 = 0.f, b2 = 0.f, b3 = 0.f;
#pragma unroll 8
        for (int k = 0; k < 256; k += 4) {
            b0 += cp[(size_t)(k + 0) * DIM + c];
            b1 += cp[(size_t)(k + 1) * DIM + c];
            b2 += cp[(size_t)(k + 2) * DIM + c];
            b3 += cp[(size_t)(k + 3) * DIM + c];
        }
        double sc = (double)b0 + (double)b1 + (double)b2 + (double)b3;
        s2 += sc * sc;
    }

    auto blkreduce = [&](double v) -> double {
#pragma unroll
        for (int off = 32; off; off >>= 1) v += __shfl_down(v, off);
        __syncthreads();
        if (lane == 0) red[w] = v;
        __syncthreads();
        return red[0] + red[1] + red[2] + red[3];
    };
    double sumsq = blkreduce(ssq);
    double s2t = blkreduce(s2);

    if (tid < 5) {
        const double nn = (double)NTOT;
        double bw = (2.0 * nn * sumsq - 2.0 * s2t) / (nn * nn - nn);
        const double fac[5] = {0.25, 0.5, 1.0, 2.0, 4.0};
        scales[tid] = (float)(-1.0 / (bw * fac[tid] + 1e-8));
    }
    if (tid == 5) *accum = 0.0;
    __threadfence();                       // release scales before k_mmd reads
}

// k_mmd: LDS-free gram + kernel-sum. Barrier-free K-loop; fragments stream from
// fragment-major Tb to VGPRs via saddr-form dwordx4 (u32 per-lane offsets).
__global__ __launch_bounds__(256) void k_mmd(const u16* __restrict__ Tb,
                                             const float* __restrict__ sq,
                                             const float* __restrict__ scales,
                                             double* __restrict__ accum,
                                             u32* __restrict__ counter,
                                             float* __restrict__ out) {
    __shared__ double red[4];

    // XCD-aware bijective swizzle (2080 = 8*260), then triangular decomposition.
    const int orig = blockIdx.x;
    const int t = (orig & 7) * 260 + (orig >> 3);
    int bi = (int)((sqrtf(8.0f * (float)t + 1.0f) - 1.0f) * 0.5f);
    while ((bi + 1) * (bi + 2) / 2 <= t) ++bi;
    while (bi * (bi + 1) / 2 > t) --bi;
    const int bj = t - bi * (bi + 1) / 2;

    const int tid = threadIdx.x;
    const int wid = tid >> 6, lane = tid & 63;
    const int wr = wid >> 1, wc = wid & 1;
    const int fr = lane & 15, fq = lane >> 4;

    f32x4 acc[4][4];
#pragma unroll
    for (int m = 0; m < 4; ++m)
#pragma unroll
        for (int n = 0; n < 4; ++n) acc[m][n] = (f32x4){0.f, 0.f, 0.f, 0.f};

    // u32 byte offsets from one uniform base (saddr-form loads, 1 VGPR each).
    const char* Tbc = (const char*)Tb;
    u32 offA[4], offB[4];
#pragma unroll
    for (int m = 0; m < 4; ++m)
        offA[m] = (u32)(((bi * 8 + wr * 4 + m) * 16 * 512 + lane * 8) * 2);
#pragma unroll
    for (int n = 0; n < 4; ++n)
        offB[n] = (u32)(((bj * 8 + wc * 4 + n) * 16 * 512 + lane * 8) * 2);

#pragma unroll
    for (int kt = 0; kt < 16; ++kt) {
        bf16x8 af[4], bfr[4];
#pragma unroll
        for (int m = 0; m < 4; ++m)
            af[m] = *(const bf16x8*)(Tbc + offA[m] + kt * 1024);
#pragma unroll
        for (int n = 0; n < 4; ++n)
            bfr[n] = *(const bf16x8*)(Tbc + offB[n] + kt * 1024);
#pragma unroll
        for (int m = 0; m < 4; ++m)
#pragma unroll
            for (int n = 0; n < 4; ++n)
                acc[m][n] = __builtin_amdgcn_mfma_f32_16x16x32_bf16(af[m], bfr[n], acc[m][n], 0, 0, 0);
    }

    // epilogue: l2 -> 5x __expf -> f32 per-thread sum -> f64 block reduce.
    const float c0 = scales[0], c1 = scales[1], c2 = scales[2], c3 = scales[3], c4 = scales[4];
    const int rowA0 = bi * 128, rowB0 = bj * 128;
    float sqc[4];
#pragma unroll
    for (int n = 0; n < 4; ++n) sqc[n] = sq[rowB0 + wc * 64 + n * 16 + fr];

    float facc = 0.f;
#pragma unroll
    for (int m = 0; m < 4; ++m) {
        float4 s4 = *(const float4*)(sq + rowA0 + wr * 64 + m * 16 + fq * 4);
        float sqr[4] = {s4.x, s4.y, s4.z, s4.w};
#pragma unroll
        for (int n = 0; n < 4; ++n) {
#pragma unroll
            for (int r = 0; r < 4; ++r) {
                float g = acc[m][n][r];
                float l2 = fmaxf(sqr[r] + sqc[n] - 2.0f * g, 0.0f);
                facc += __expf(c0 * l2) + __expf(c1 * l2) + __expf(c2 * l2)
                      + __expf(c3 * l2) + __expf(c4 * l2);
            }
        }
    }

    const double wfac = ((bi == bj) ? 1.0 : 2.0) *
                        (((bi < 32) == (bj < 32)) ? 1.0 : -1.0);
    double lacc = (double)facc;
#pragma unroll
    for (int off = 32; off; off >>= 1) lacc += __shfl_down(lacc, off);
    if (lane == 0) red[wid] = lacc;
    __syncthreads();

    if (tid == 0) {
        atomicAdd(accum, (red[0] + red[1] + red[2] + red[3]) * wfac);
        __threadfence();
        u32 done = atomicAdd(counter, 1u);
        if (done == 2079u) {
            double tot = atomicAdd(accum, 0.0);   // device-scope coherent read
            out[0] = (float)(tot / ((double)NS * (double)NS));
        }
    }
}

extern "C" void kernel_launch(void* const* d_in, const int* in_sizes, int n_in,
                              void* d_out, int out_size, void* d_ws, size_t ws_size,
                              hipStream_t stream) {
    const float* src = (const float*)d_in[0];
    const float* tgt = (const float*)d_in[1];
    char* ws = (char*)d_ws;

    const size_t MB8 = 8u * 1024 * 1024;
    u16* Tb        = (u16*)ws;                                 // 8 MiB fragment-major
    float* sq      = (float*)(ws + MB8);                       // 32 KiB
    float* cp      = (float*)(ws + MB8 + 32 * 1024);           // 512 KiB
    float* scales  = (float*)(ws + MB8 + 544 * 1024);          // 32 B
    double* accum  = (double*)(ws + MB8 + 544 * 1024 + 64);    // 8 B
    u32* mmd_ctr   = (u32*)(ws + MB8 + 544 * 1024 + 72);       // 4 B
    u32* prep_ctr  = (u32*)(ws + MB8 + 544 * 1024 + 76);       // 4 B

    hipMemsetAsync(accum, 0, 16, stream);   // accum + mmd_ctr + prep_ctr
    k_prep<<<256, 256, 0, stream>>>(src, tgt, Tb, sq, cp, scales, accum, prep_ctr);
    k_mmd<<<2080, 256, 0, stream>>>(Tb, sq, scales, accum, mmd_ctr, (float*)d_out);
}

// Round 8
// 199.587 us; speedup vs baseline: 1.1071x; 1.1025x over previous
//
#include <hip/hip_runtime.h>
#include <stdint.h>

typedef uint16_t u16;
typedef uint32_t u32;

#define NS 4096
#define NTOT 8192
#define DIM 512
#define NTILE 2080
#define GRID_MMD 1024

typedef __attribute__((ext_vector_type(8))) short bf16x8;
typedef __attribute__((ext_vector_type(4))) float f32x4;

__device__ inline u16 f2bf(float f) {
    u32 u = __float_as_uint(f);
    return (u16)((u + 0x7fffu + ((u >> 16) & 1u)) >> 16);
}

__device__ inline void load_lds16(const void* g, void* l) {
    __builtin_amdgcn_global_load_lds((__attribute__((address_space(1))) void*)g,
                                     (__attribute__((address_space(3))) void*)l,
                                     16, 0, 0);
}

// Fragment-major Tb: fragment (rb, kt) = 16 rows x 32 cols bf16, contiguous 1 KiB at
// Tb + (rb*16+kt)*512 (u16); u16 offset (fq*16+fr)*8 holds row rb*16+fr, k-octet fq.

// k_prep: 256 blocks x 256 thr; block = 32 rows. bf16 conversion via LDS transpose,
// per-row sumsq, per-block colsum partials. LAST block computes bandwidth scales.
__global__ __launch_bounds__(256) void k_prep(const float* __restrict__ src,
                                              const float* __restrict__ tgt,
                                              u16* __restrict__ Tb,
                                              float* __restrict__ sq,
                                              float* __restrict__ cp,
                                              float* __restrict__ scales,
                                              double* __restrict__ accum,
                                              u32* __restrict__ ctr) {
    __shared__ u16 xb[2][16][520];
    __shared__ float cs_l[4][DIM];
    __shared__ int lastflag;
    __shared__ double red[4];
    const int b = blockIdx.x, tid = threadIdx.x;
    const int w = tid >> 6, lane = tid & 63;
    const int rbl = w >> 1;
    const int i0 = (w & 1) * 8;

    float cs[8];
#pragma unroll
    for (int e = 0; e < 8; ++e) cs[e] = 0.f;

#pragma unroll
    for (int i = 0; i < 8; ++i) {
        const int fr = i0 + i;
        const int r = b * 32 + rbl * 16 + fr;
        const float* rowp = (r < NS) ? (src + (size_t)r * DIM)
                                     : (tgt + (size_t)(r - NS) * DIM);
        float4 v0 = *(const float4*)(rowp + lane * 8);
        float4 v1 = *(const float4*)(rowp + lane * 8 + 4);
        float vx[8] = {v0.x, v0.y, v0.z, v0.w, v1.x, v1.y, v1.z, v1.w};
        float ss = 0.f;
#pragma unroll
        for (int e = 0; e < 8; ++e) { ss += vx[e] * vx[e]; cs[e] += vx[e]; }
        u32 pk[4];
#pragma unroll
        for (int e = 0; e < 4; ++e)
            pk[e] = (u32)f2bf(vx[2 * e]) | ((u32)f2bf(vx[2 * e + 1]) << 16);
        *(uint4*)&xb[rbl][fr][lane * 8] = make_uint4(pk[0], pk[1], pk[2], pk[3]);
#pragma unroll
        for (int off = 32; off; off >>= 1) ss += __shfl_down(ss, off);
        if (lane == 0) sq[r] = ss;
    }
#pragma unroll
    for (int e = 0; e < 8; ++e) cs_l[w][lane * 8 + e] = cs[e];
    __syncthreads();

    const int fq = lane >> 4, frx = lane & 15;
    const int rbg = b * 2 + rbl;
#pragma unroll
    for (int tt = 0; tt < 8; ++tt) {
        const int kt = (w & 1) * 8 + tt;
        uint4 v = *(const uint4*)&xb[rbl][frx][(kt * 4 + fq) * 8];
        *(uint4*)(Tb + (size_t)(rbg * 16 + kt) * 512 + lane * 8) = v;
    }

    float a0 = cs_l[0][tid] + cs_l[1][tid] + cs_l[2][tid] + cs_l[3][tid];
    float a1 = cs_l[0][tid + 256] + cs_l[1][tid + 256] + cs_l[2][tid + 256] + cs_l[3][tid + 256];
    cp[(size_t)b * DIM + tid] = a0;
    cp[(size_t)b * DIM + tid + 256] = a1;

    // ---- fused bandwidth tail: last-done block reduces cp+sq -> scales ----
    __threadfence();
    if (tid == 0) lastflag = (atomicAdd(ctr, 1u) == 255u) ? 1 : 0;
    __syncthreads();
    if (!lastflag) return;
    __threadfence();

    double ssq = 0.0;
    for (int i = tid; i < NTOT; i += 256) ssq += (double)sq[i];

    double s2 = 0.0;
#pragma unroll
    for (int cc = 0; cc < 2; ++cc) {
        const int c = tid + cc * 256;
        float b0 = 0.f, b1 = 0.f, b2 = 0.f, b3 = 0.f;
#pragma unroll 8
        for (int k = 0; k < 256; k += 4) {
            b0 += cp[(size_t)(k + 0) * DIM + c];
            b1 += cp[(size_t)(k + 1) * DIM + c];
            b2 += cp[(size_t)(k + 2) * DIM + c];
            b3 += cp[(size_t)(k + 3) * DIM + c];
        }
        double sc = (double)b0 + (double)b1 + (double)b2 + (double)b3;
        s2 += sc * sc;
    }

    auto blkreduce = [&](double v) -> double {
#pragma unroll
        for (int off = 32; off; off >>= 1) v += __shfl_down(v, off);
        __syncthreads();
        if (lane == 0) red[w] = v;
        __syncthreads();
        return red[0] + red[1] + red[2] + red[3];
    };
    double sumsq = blkreduce(ssq);
    double s2t = blkreduce(s2);

    if (tid < 5) {
        const double nn = (double)NTOT;
        double bw = (2.0 * nn * sumsq - 2.0 * s2t) / (nn * nn - nn);
        const double fac[5] = {0.25, 0.5, 1.0, 2.0, 4.0};
        scales[tid] = (float)(-1.0 / (bw * fac[tid] + 1e-8));
    }
    if (tid == 5) *accum = 0.0;
    __threadfence();
}

// k_mmd: PERSISTENT blocks (1024), each grid-strides 2-3 triangular tiles.
// 128x128 tile, fragment-major LDS staging (conflict-free), 2-phase dbuf,
// exp-chain epilogue (1 exp + 2 sqrt per entry for all 5 bandwidths).
__global__ __launch_bounds__(256) void k_mmd(const u16* __restrict__ Tb,
                                             const float* __restrict__ sq,
                                             const float* __restrict__ scales,
                                             double* __restrict__ accum,
                                             u32* __restrict__ counter,
                                             float* __restrict__ out) {
    __shared__ __align__(16) u16 As[2][4096];
    __shared__ __align__(16) u16 Bs[2][4096];
    __shared__ double red[4];

    const int tid = threadIdx.x;
    const int wid = tid >> 6, lane = tid & 63;
    const int wr = wid >> 1, wc = wid & 1;
    const int fr = lane & 15, fq = lane >> 4;
    const float s2c = scales[2];   // middle bandwidth scale; others = {4,2,1,.5,.25}x

    double lacc_tot = 0.0;

    for (int t = blockIdx.x; t < NTILE; t += GRID_MMD) {
        int bi = (int)((sqrtf(8.0f * (float)t + 1.0f) - 1.0f) * 0.5f);
        while ((bi + 1) * (bi + 2) / 2 <= t) ++bi;
        while (bi * (bi + 1) / 2 > t) --bi;
        const int bj = t - bi * (bi + 1) / 2;

        f32x4 acc[4][4];
#pragma unroll
        for (int m = 0; m < 4; ++m)
#pragma unroll
            for (int n = 0; n < 4; ++n) acc[m][n] = (f32x4){0.f, 0.f, 0.f, 0.f};

        // per-lane contiguous sources: frag (rb + chunk, kt) base + lane*16B
        int offA[2], offB[2];
#pragma unroll
        for (int q = 0; q < 2; ++q) {
            offA[q] = (bi * 8 + wid * 2 + q) * 16 * 512 + lane * 8;
            offB[q] = (bj * 8 + wid * 2 + q) * 16 * 512 + lane * 8;
        }

        auto stage = [&](int buf, int kt) {
#pragma unroll
            for (int q = 0; q < 2; ++q) {
                load_lds16(Tb + offA[q] + kt * 512, &As[buf][(wid * 2 + q) * 512]);
                load_lds16(Tb + offB[q] + kt * 512, &Bs[buf][(wid * 2 + q) * 512]);
            }
        };
        auto compute = [&](int buf) {
            bf16x8 af[4], bfr[4];
#pragma unroll
            for (int m = 0; m < 4; ++m)
                af[m] = *(const bf16x8*)(&As[buf][(wr * 4 + m) * 512] + lane * 8);
#pragma unroll
            for (int n = 0; n < 4; ++n)
                bfr[n] = *(const bf16x8*)(&Bs[buf][(wc * 4 + n) * 512] + lane * 8);
#pragma unroll
            for (int m = 0; m < 4; ++m)
#pragma unroll
                for (int n = 0; n < 4; ++n)
                    acc[m][n] = __builtin_amdgcn_mfma_f32_16x16x32_bf16(af[m], bfr[n], acc[m][n], 0, 0, 0);
        };

        stage(0, 0);
        __syncthreads();
        for (int kt = 0; kt < 15; ++kt) {
            stage((kt & 1) ^ 1, kt + 1);
            compute(kt & 1);
            __syncthreads();
        }
        compute(1);

        // epilogue: l2 -> exp-chain -> f32 sum -> f64 block reduce
        const int rowA0 = bi * 128, rowB0 = bj * 128;
        float sqc[4];
#pragma unroll
        for (int n = 0; n < 4; ++n) sqc[n] = sq[rowB0 + wc * 64 + n * 16 + fr];

        float facc = 0.f;
#pragma unroll
        for (int m = 0; m < 4; ++m) {
            float4 s4 = *(const float4*)(sq + rowA0 + wr * 64 + m * 16 + fq * 4);
            float sqr[4] = {s4.x, s4.y, s4.z, s4.w};
#pragma unroll
            for (int n = 0; n < 4; ++n) {
#pragma unroll
                for (int r = 0; r < 4; ++r) {
                    float g = acc[m][n][r];
                    float l2 = fmaxf(sqr[r] + sqc[n] - 2.0f * g, 0.0f);
                    float e = __expf(s2c * l2);        // k2
                    float e2 = e * e;                   // k1
                    float e4 = e2 * e2;                 // k0
                    float r1, r2;
                    asm("v_sqrt_f32 %0, %1" : "=v"(r1) : "v"(e));   // k3
                    asm("v_sqrt_f32 %0, %1" : "=v"(r2) : "v"(r1));  // k4
                    facc += e4 + e2 + e + r1 + r2;
                }
            }
        }

        const double wfac = ((bi == bj) ? 1.0 : 2.0) *
                            (((bi < 32) == (bj < 32)) ? 1.0 : -1.0);
        double lacc = (double)facc;
#pragma unroll
        for (int off = 32; off; off >>= 1) lacc += __shfl_down(lacc, off);
        if (lane == 0) red[wid] = lacc;
        __syncthreads();
        if (tid == 0) lacc_tot += (red[0] + red[1] + red[2] + red[3]) * wfac;
        __syncthreads();
    }

    if (tid == 0) {
        atomicAdd(accum, lacc_tot);
        __threadfence();
        u32 done = atomicAdd(counter, 1u);
        if (done == GRID_MMD - 1) {
            double tot = atomicAdd(accum, 0.0);
            out[0] = (float)(tot / ((double)NS * (double)NS));
        }
    }
}

extern "C" void kernel_launch(void* const* d_in, const int* in_sizes, int n_in,
                              void* d_out, int out_size, void* d_ws, size_t ws_size,
                              hipStream_t stream) {
    const float* src = (const float*)d_in[0];
    const float* tgt = (const float*)d_in[1];
    char* ws = (char*)d_ws;

    const size_t MB8 = 8u * 1024 * 1024;
    u16* Tb        = (u16*)ws;                                 // 8 MiB fragment-major
    float* sq      = (float*)(ws + MB8);                       // 32 KiB
    float* cp      = (float*)(ws + MB8 + 32 * 1024);           // 512 KiB
    float* scales  = (float*)(ws + MB8 + 544 * 1024);          // 32 B
    double* accum  = (double*)(ws + MB8 + 544 * 1024 + 64);    // 8 B
    u32* mmd_ctr   = (u32*)(ws + MB8 + 544 * 1024 + 72);       // 4 B
    u32* prep_ctr  = (u32*)(ws + MB8 + 544 * 1024 + 76);       // 4 B

    hipMemsetAsync(accum, 0, 16, stream);   // accum + mmd_ctr + prep_ctr
    k_prep<<<256, 256, 0, stream>>>(src, tgt, Tb, sq, cp, scales, accum, prep_ctr);
    k_mmd<<<GRID_MMD, 256, 0, stream>>>(Tb, sq, scales, accum, mmd_ctr, (float*)d_out);
}

// Round 9
// 156.006 us; speedup vs baseline: 1.4163x; 1.2793x over previous
//
#include <hip/hip_runtime.h>
#include <stdint.h>

typedef uint16_t u16;
typedef uint32_t u32;

#define NS 4096
#define NTOT 8192
#define DIM 512
#define NTILE 2080
#define GRID_MMD 1024

typedef __attribute__((ext_vector_type(8))) short bf16x8;
typedef __attribute__((ext_vector_type(4))) float f32x4;

__device__ inline u16 f2bf(float f) {
    u32 u = __float_as_uint(f);
    return (u16)((u + 0x7fffu + ((u >> 16) & 1u)) >> 16);
}

__device__ inline void load_lds16(const void* g, void* l) {
    __builtin_amdgcn_global_load_lds((__attribute__((address_space(1))) void*)g,
                                     (__attribute__((address_space(3))) void*)l,
                                     16, 0, 0);
}

// Fragment-major Tb: fragment (rb, kt) = 16 rows x 32 cols bf16, contiguous 1 KiB at
// Tb + (rb*16+kt)*512 (u16); u16 offset (fq*16+fr)*8 holds row rb*16+fr, k-octet fq.

// k_prep: 256 blocks x 256 thr; block = 32 rows. bf16 conversion via LDS transpose
// (contiguous 1 KiB stores), per-row sumsq, per-block colsum partials. No fences.
__global__ __launch_bounds__(256) void k_prep(const float* __restrict__ src,
                                              const float* __restrict__ tgt,
                                              u16* __restrict__ Tb,
                                              float* __restrict__ sq,
                                              float* __restrict__ cp) {
    __shared__ u16 xb[2][16][520];
    __shared__ float cs_l[4][DIM];
    const int b = blockIdx.x, tid = threadIdx.x;
    const int w = tid >> 6, lane = tid & 63;
    const int rbl = w >> 1;
    const int i0 = (w & 1) * 8;

    float cs[8];
#pragma unroll
    for (int e = 0; e < 8; ++e) cs[e] = 0.f;

#pragma unroll
    for (int i = 0; i < 8; ++i) {
        const int fr = i0 + i;
        const int r = b * 32 + rbl * 16 + fr;
        const float* rowp = (r < NS) ? (src + (size_t)r * DIM)
                                     : (tgt + (size_t)(r - NS) * DIM);
        float4 v0 = *(const float4*)(rowp + lane * 8);
        float4 v1 = *(const float4*)(rowp + lane * 8 + 4);
        float vx[8] = {v0.x, v0.y, v0.z, v0.w, v1.x, v1.y, v1.z, v1.w};
        float ss = 0.f;
#pragma unroll
        for (int e = 0; e < 8; ++e) { ss += vx[e] * vx[e]; cs[e] += vx[e]; }
        u32 pk[4];
#pragma unroll
        for (int e = 0; e < 4; ++e)
            pk[e] = (u32)f2bf(vx[2 * e]) | ((u32)f2bf(vx[2 * e + 1]) << 16);
        *(uint4*)&xb[rbl][fr][lane * 8] = make_uint4(pk[0], pk[1], pk[2], pk[3]);
#pragma unroll
        for (int off = 32; off; off >>= 1) ss += __shfl_down(ss, off);
        if (lane == 0) sq[r] = ss;
    }
#pragma unroll
    for (int e = 0; e < 8; ++e) cs_l[w][lane * 8 + e] = cs[e];
    __syncthreads();

    const int fq = lane >> 4, frx = lane & 15;
    const int rbg = b * 2 + rbl;
#pragma unroll
    for (int tt = 0; tt < 8; ++tt) {
        const int kt = (w & 1) * 8 + tt;
        uint4 v = *(const uint4*)&xb[rbl][frx][(kt * 4 + fq) * 8];
        *(uint4*)(Tb + (size_t)(rbg * 16 + kt) * 512 + lane * 8) = v;
    }

    float a0 = cs_l[0][tid] + cs_l[1][tid] + cs_l[2][tid] + cs_l[3][tid];
    float a1 = cs_l[0][tid + 256] + cs_l[1][tid + 256] + cs_l[2][tid + 256] + cs_l[3][tid + 256];
    cp[(size_t)b * DIM + tid] = a0;
    cp[(size_t)b * DIM + tid + 256] = a1;
}

// k_band: 1 block; bandwidth via sum(l2) = 2*N*sum(sq) - 2*||colsum||^2.
// Writes 5 scales (natural-log form), zeroes accum.
__global__ __launch_bounds__(256) void k_band(const float* __restrict__ sq,
                                              const float* __restrict__ cp,
                                              float* __restrict__ scales,
                                              double* __restrict__ accum) {
    __shared__ double red[4];
    const int tid = threadIdx.x;
    const int w = tid >> 6, lane = tid & 63;

    double ssq = 0.0;
    for (int i = tid; i < NTOT; i += 256) ssq += (double)sq[i];

    double s2 = 0.0;
#pragma unroll
    for (int cc = 0; cc < 2; ++cc) {
        const int c = tid + cc * 256;
        float b0 = 0.f, b1 = 0.f, b2 = 0.f, b3 = 0.f;
#pragma unroll 8
        for (int k = 0; k < 256; k += 4) {
            b0 += cp[(size_t)(k + 0) * DIM + c];
            b1 += cp[(size_t)(k + 1) * DIM + c];
            b2 += cp[(size_t)(k + 2) * DIM + c];
            b3 += cp[(size_t)(k + 3) * DIM + c];
        }
        double sc = (double)b0 + (double)b1 + (double)b2 + (double)b3;
        s2 += sc * sc;
    }

    auto blkreduce = [&](double v) -> double {
#pragma unroll
        for (int off = 32; off; off >>= 1) v += __shfl_down(v, off);
        __syncthreads();
        if (lane == 0) red[w] = v;
        __syncthreads();
        return red[0] + red[1] + red[2] + red[3];
    };
    double sumsq = blkreduce(ssq);
    double s2t = blkreduce(s2);

    if (tid < 5) {
        const double nn = (double)NTOT;
        double bw = (2.0 * nn * sumsq - 2.0 * s2t) / (nn * nn - nn);
        const double fac[5] = {0.25, 0.5, 1.0, 2.0, 4.0};
        scales[tid] = (float)(-1.0 / (bw * fac[tid] + 1e-8));
    }
    if (tid == 5) *accum = 0.0;
}

// k_mmd: persistent blocks, XCD-chunked contiguous tile ranges, 128x128 tile,
// fragment-major LDS, 3-buffer pipeline with counted vmcnt (T4), exp-chain epilogue.
__global__ __launch_bounds__(256) void k_mmd(const u16* __restrict__ Tb,
                                             const float* __restrict__ sq,
                                             const float* __restrict__ scales,
                                             double* __restrict__ accum) {
    __shared__ __align__(16) u16 As[3][4096];
    __shared__ __align__(16) u16 Bs[3][4096];
    __shared__ double red[4];

    const int tid = threadIdx.x;
    const int wid = tid >> 6, lane = tid & 63;
    const int wr = wid >> 1, wc = wid & 1;
    const int fr = lane & 15, fq = lane >> 4;
    const float s2c = scales[2];

    // XCD-chunked static partition: XCD x owns a contiguous 1/8 of the triangle.
    const int b = (int)blockIdx.x;
    const int bp = (b & 7) * (GRID_MMD / 8) + (b >> 3);
    const int lo = (bp * 65) >> 5;          // bp*NTILE/GRID_MMD
    const int hi = ((bp + 1) * 65) >> 5;

    double lacc_tot = 0.0;

    for (int t = lo; t < hi; ++t) {
        int bi = (int)((sqrtf(8.0f * (float)t + 1.0f) - 1.0f) * 0.5f);
        while ((bi + 1) * (bi + 2) / 2 <= t) ++bi;
        while (bi * (bi + 1) / 2 > t) --bi;
        const int bj = t - bi * (bi + 1) / 2;

        int offA[2], offB[2];
#pragma unroll
        for (int q = 0; q < 2; ++q) {
            offA[q] = (bi * 8 + wid * 2 + q) * 16 * 512 + lane * 8;
            offB[q] = (bj * 8 + wid * 2 + q) * 16 * 512 + lane * 8;
        }

        auto stage = [&](int buf, int kt) {
#pragma unroll
            for (int q = 0; q < 2; ++q) {
                load_lds16(Tb + offA[q] + kt * 512, &As[buf][(wid * 2 + q) * 512]);
                load_lds16(Tb + offB[q] + kt * 512, &Bs[buf][(wid * 2 + q) * 512]);
            }
        };

        f32x4 acc[4][4];
#pragma unroll
        for (int m = 0; m < 4; ++m)
#pragma unroll
            for (int n = 0; n < 4; ++n) acc[m][n] = (f32x4){0.f, 0.f, 0.f, 0.f};

        // barrier: prev tile's compute(15) (read of buf0) done in ALL waves
        // before this tile's stage(0) overwrites it.
        __builtin_amdgcn_s_barrier();
        asm volatile("" ::: "memory");

        stage(0, 0);
        stage(1, 1);

#pragma unroll
        for (int u = 0; u < 16; ++u) {
            // step-u's 4 loads retired; step-(u+1)'s may stay in flight.
            if (u == 15) asm volatile("s_waitcnt vmcnt(0)" ::: "memory");
            else         asm volatile("s_waitcnt vmcnt(4)" ::: "memory");
            __builtin_amdgcn_s_barrier();
            asm volatile("" ::: "memory");   // keep ds_reads below the barrier

            const u16* Ab = As[u % 3];
            const u16* Bb = Bs[u % 3];
            bf16x8 af[4], bfr[4];
#pragma unroll
            for (int m = 0; m < 4; ++m)
                af[m] = *(const bf16x8*)(Ab + (wr * 4 + m) * 512 + lane * 8);
#pragma unroll
            for (int n = 0; n < 4; ++n)
                bfr[n] = *(const bf16x8*)(Bb + (wc * 4 + n) * 512 + lane * 8);
#pragma unroll
            for (int m = 0; m < 4; ++m)
#pragma unroll
                for (int n = 0; n < 4; ++n)
                    acc[m][n] = __builtin_amdgcn_mfma_f32_16x16x32_bf16(af[m], bfr[n], acc[m][n], 0, 0, 0);

            if (u + 2 < 16) stage((u + 2) % 3, u + 2);
        }

        // epilogue: l2 -> exp-chain (1 exp + 2 sqrt for all 5 bandwidths) -> f32 sum
        const int rowA0 = bi * 128, rowB0 = bj * 128;
        float sqc[4];
#pragma unroll
        for (int n = 0; n < 4; ++n) sqc[n] = sq[rowB0 + wc * 64 + n * 16 + fr];

        float facc = 0.f;
#pragma unroll
        for (int m = 0; m < 4; ++m) {
            float4 s4 = *(const float4*)(sq + rowA0 + wr * 64 + m * 16 + fq * 4);
            float sqr[4] = {s4.x, s4.y, s4.z, s4.w};
#pragma unroll
            for (int n = 0; n < 4; ++n) {
#pragma unroll
                for (int r = 0; r < 4; ++r) {
                    float g = acc[m][n][r];
                    float l2 = fmaxf(sqr[r] + sqc[n] - 2.0f * g, 0.0f);
                    float e = __expf(s2c * l2);
                    float e2 = e * e;
                    float e4 = e2 * e2;
                    float r1, r2;
                    asm("v_sqrt_f32 %0, %1" : "=v"(r1) : "v"(e));
                    asm("v_sqrt_f32 %0, %1" : "=v"(r2) : "v"(r1));
                    facc += e4 + e2 + e + r1 + r2;
                }
            }
        }

        const double wfac = ((bi == bj) ? 1.0 : 2.0) *
                            (((bi < 32) == (bj < 32)) ? 1.0 : -1.0);
        lacc_tot += (double)facc * wfac;
    }

    // single end-of-kernel block reduce -> one atomicAdd per block
    double v = lacc_tot;
#pragma unroll
    for (int off = 32; off; off >>= 1) v += __shfl_down(v, off);
    __syncthreads();
    if (lane == 0) red[wid] = v;
    __syncthreads();
    if (tid == 0)
        atomicAdd(accum, red[0] + red[1] + red[2] + red[3]);
}

// k_final: scalar finish (kernel boundary provides device-wide visibility).
__global__ void k_final(const double* __restrict__ accum, float* __restrict__ out) {
    if (threadIdx.x == 0)
        out[0] = (float)(accum[0] / ((double)NS * (double)NS));
}

extern "C" void kernel_launch(void* const* d_in, const int* in_sizes, int n_in,
                              void* d_out, int out_size, void* d_ws, size_t ws_size,
                              hipStream_t stream) {
    const float* src = (const float*)d_in[0];
    const float* tgt = (const float*)d_in[1];
    char* ws = (char*)d_ws;

    const size_t MB8 = 8u * 1024 * 1024;
    u16* Tb       = (u16*)ws;                                 // 8 MiB fragment-major
    float* sq     = (float*)(ws + MB8);                       // 32 KiB
    float* cp     = (float*)(ws + MB8 + 32 * 1024);           // 512 KiB
    float* scales = (float*)(ws + MB8 + 544 * 1024);          // 32 B
    double* accum = (double*)(ws + MB8 + 544 * 1024 + 64);    // 8 B

    k_prep<<<256, 256, 0, stream>>>(src, tgt, Tb, sq, cp);
    k_band<<<1, 256, 0, stream>>>(sq, cp, scales, accum);
    k_mmd<<<GRID_MMD, 256, 0, stream>>>(Tb, sq, scales, accum);
    k_final<<<1, 64, 0, stream>>>(accum, (float*)d_out);
}

// Round 11
// 145.965 us; speedup vs baseline: 1.5137x; 1.0688x over previous
//
#include <hip/hip_runtime.h>
#include <stdint.h>

typedef uint8_t u8;
typedef uint16_t u16;
typedef uint32_t u32;
typedef unsigned long long u64;

#define NS 4096
#define NTOT 8192
#define DIM 512
#define NTILE 2080
#define GRID_MMD 1024

typedef __attribute__((ext_vector_type(2))) long l64x2;
typedef __attribute__((ext_vector_type(4))) float f32x4;

__device__ inline void load_lds16(const void* g, void* l) {
    __builtin_amdgcn_global_load_lds((__attribute__((address_space(1))) void*)g,
                                     (__attribute__((address_space(3))) void*)l,
                                     16, 0, 0);
}

// fp8 fragment-major Tb: fragment (rb, kt2) = 16 rows x 64 k in e4m3, contiguous
// 1 KiB at Tb + (rb*8+kt2)*1024. Lane l's 16 B = [sub-step0 8B | sub-step1 8B]:
// byte (l*16 + s*8 + e) = fp8 of row rb*16+(l&15), k = kt2*64 + s*32 + (l>>4)*8 + e.
// One ds_read_b128 per lane feeds TWO mfma_f32_16x16x32_fp8_fp8 (K-steps 2u, 2u+1).

// k_prep: 256 blocks x 256 thr; block = 32 rows. fp8 conversion via LDS transpose
// (contiguous 1 KiB frag stores), per-row sumsq (f32-exact), per-block colsums.
__global__ __launch_bounds__(256) void k_prep(const float* __restrict__ src,
                                              const float* __restrict__ tgt,
                                              u8* __restrict__ Tb,
                                              float* __restrict__ sq,
                                              float* __restrict__ cp) {
    __shared__ u8 xb[2][16][528];       // 528 = 512 + 16B pad
    __shared__ float cs_l[4][DIM];
    const int b = blockIdx.x, tid = threadIdx.x;
    const int w = tid >> 6, lane = tid & 63;
    const int rbl = w >> 1;
    const int i0 = (w & 1) * 8;

    float cs[8];
#pragma unroll
    for (int e = 0; e < 8; ++e) cs[e] = 0.f;

#pragma unroll
    for (int i = 0; i < 8; ++i) {
        const int fr = i0 + i;
        const int r = b * 32 + rbl * 16 + fr;
        const float* rowp = (r < NS) ? (src + (size_t)r * DIM)
                                     : (tgt + (size_t)(r - NS) * DIM);
        float4 v0 = *(const float4*)(rowp + lane * 8);
        float4 v1 = *(const float4*)(rowp + lane * 8 + 4);
        float vx[8] = {v0.x, v0.y, v0.z, v0.w, v1.x, v1.y, v1.z, v1.w};
        float ss = 0.f;
#pragma unroll
        for (int e = 0; e < 8; ++e) { ss += vx[e] * vx[e]; cs[e] += vx[e]; }
        int dlo = 0, dhi = 0;
        dlo = __builtin_amdgcn_cvt_pk_fp8_f32(vx[0], vx[1], dlo, 0);
        dlo = __builtin_amdgcn_cvt_pk_fp8_f32(vx[2], vx[3], dlo, 1);
        dhi = __builtin_amdgcn_cvt_pk_fp8_f32(vx[4], vx[5], dhi, 0);
        dhi = __builtin_amdgcn_cvt_pk_fp8_f32(vx[6], vx[7], dhi, 1);
        *(u32*)&xb[rbl][fr][lane * 8] = (u32)dlo;
        *(u32*)&xb[rbl][fr][lane * 8 + 4] = (u32)dhi;
#pragma unroll
        for (int off = 32; off; off >>= 1) ss += __shfl_down(ss, off);
        if (lane == 0) sq[r] = ss;
    }
#pragma unroll
    for (int e = 0; e < 8; ++e) cs_l[w][lane * 8 + e] = cs[e];
    __syncthreads();

    // frag writes: wave w -> frags w*4..w*4+3 (f: rbl=f>>3, kt2=f&7), coalesced 1 KiB.
    const int row = lane & 15, oct = lane >> 4;
#pragma unroll
    for (int ff = 0; ff < 4; ++ff) {
        const int f = w * 4 + ff;
        const int frbl = f >> 3, kt2 = f & 7;
        u64 a0 = *(const u64*)&xb[frbl][row][kt2 * 64 + oct * 8];
        u64 a1 = *(const u64*)&xb[frbl][row][kt2 * 64 + 32 + oct * 8];
        const int rbg = b * 2 + frbl;
        u8* dst = Tb + (size_t)(rbg * 8 + kt2) * 1024 + lane * 16;
        *(u64*)dst = a0;
        *(u64*)(dst + 8) = a1;
    }

    float a0 = cs_l[0][tid] + cs_l[1][tid] + cs_l[2][tid] + cs_l[3][tid];
    float a1 = cs_l[0][tid + 256] + cs_l[1][tid + 256] + cs_l[2][tid + 256] + cs_l[3][tid + 256];
    cp[(size_t)b * DIM + tid] = a0;
    cp[(size_t)b * DIM + tid + 256] = a1;
}

// k_band: 1 block; bandwidth via sum(l2) = 2*N*sum(sq) - 2*||colsum||^2.
// Writes 5 natural-log scales; zeroes accum + k_mmd counter.
__global__ __launch_bounds__(256) void k_band(const float* __restrict__ sq,
                                              const float* __restrict__ cp,
                                              float* __restrict__ scales,
                                              double* __restrict__ accum,
                                              u32* __restrict__ counter) {
    __shared__ double red[4];
    const int tid = threadIdx.x;
    const int w = tid >> 6, lane = tid & 63;

    double ssq = 0.0;
    for (int i = tid; i < NTOT; i += 256) ssq += (double)sq[i];

    double s2 = 0.0;
#pragma unroll
    for (int cc = 0; cc < 2; ++cc) {
        const int c = tid + cc * 256;
        float b0 = 0.f, b1 = 0.f, b2 = 0.f, b3 = 0.f;
#pragma unroll 8
        for (int k = 0; k < 256; k += 4) {
            b0 += cp[(size_t)(k + 0) * DIM + c];
            b1 += cp[(size_t)(k + 1) * DIM + c];
            b2 += cp[(size_t)(k + 2) * DIM + c];
            b3 += cp[(size_t)(k + 3) * DIM + c];
        }
        double sc = (double)b0 + (double)b1 + (double)b2 + (double)b3;
        s2 += sc * sc;
    }

    auto blkreduce = [&](double v) -> double {
#pragma unroll
        for (int off = 32; off; off >>= 1) v += __shfl_down(v, off);
        __syncthreads();
        if (lane == 0) red[w] = v;
        __syncthreads();
        return red[0] + red[1] + red[2] + red[3];
    };
    double sumsq = blkreduce(ssq);
    double s2t = blkreduce(s2);

    if (tid < 5) {
        const double nn = (double)NTOT;
        double bw = (2.0 * nn * sumsq - 2.0 * s2t) / (nn * nn - nn);
        const double fac[5] = {0.25, 0.5, 1.0, 2.0, 4.0};
        scales[tid] = (float)(-1.0 / (bw * fac[tid] + 1e-8));
    }
    if (tid == 5) *accum = 0.0;
    if (tid == 6) *counter = 0u;
}

// k_mmd: persistent blocks, XCD-chunked triangle, 128x128 tile, fp8 MFMA,
// 8 mega-K-steps (64 k each), 3-buffer depth-2 counted vmcnt, exp-chain epilogue,
// fused counter finish.
__global__ __launch_bounds__(256) void k_mmd(const u8* __restrict__ Tb,
                                             const float* __restrict__ sq,
                                             const float* __restrict__ scales,
                                             double* __restrict__ accum,
                                             u32* __restrict__ counter,
                                             float* __restrict__ out) {
    __shared__ __align__(16) u8 As[3][8192];
    __shared__ __align__(16) u8 Bs[3][8192];
    __shared__ double red[4];

    const int tid = threadIdx.x;
    const int wid = tid >> 6, lane = tid & 63;
    const int wr = wid >> 1, wc = wid & 1;
    const int fr = lane & 15, fq = lane >> 4;
    const float s2c = scales[2];

    const int b = (int)blockIdx.x;
    const int bp = (b & 7) * (GRID_MMD / 8) + (b >> 3);
    const int lo = (bp * 65) >> 5;
    const int hi = ((bp + 1) * 65) >> 5;

    double lacc_tot = 0.0;

    for (int t = lo; t < hi; ++t) {
        int bi = (int)((sqrtf(8.0f * (float)t + 1.0f) - 1.0f) * 0.5f);
        while ((bi + 1) * (bi + 2) / 2 <= t) ++bi;
        while (bi * (bi + 1) / 2 > t) --bi;
        const int bj = t - bi * (bi + 1) / 2;

        u32 offA[2], offB[2];
#pragma unroll
        for (int q = 0; q < 2; ++q) {
            offA[q] = (u32)((bi * 8 + wid * 2 + q) * 8) * 1024 + lane * 16;
            offB[q] = (u32)((bj * 8 + wid * 2 + q) * 8) * 1024 + lane * 16;
        }

        auto stage = [&](int buf, int u) {
#pragma unroll
            for (int q = 0; q < 2; ++q) {
                load_lds16(Tb + offA[q] + u * 1024, &As[buf][(wid * 2 + q) * 1024]);
                load_lds16(Tb + offB[q] + u * 1024, &Bs[buf][(wid * 2 + q) * 1024]);
            }
        };

        f32x4 acc[4][4];
#pragma unroll
        for (int m = 0; m < 4; ++m)
#pragma unroll
            for (int n = 0; n < 4; ++n) acc[m][n] = (f32x4){0.f, 0.f, 0.f, 0.f};

        // all waves done reading buf0 of previous tile before restaging it
        __builtin_amdgcn_s_barrier();
        asm volatile("" ::: "memory");

        stage(0, 0);
        stage(1, 1);

#pragma unroll
        for (int u = 0; u < 8; ++u) {
            // step-u's 4 loads retired; step-(u+1)'s stay in flight
            if (u == 7) asm volatile("s_waitcnt vmcnt(0)" ::: "memory");
            else        asm volatile("s_waitcnt vmcnt(4)" ::: "memory");
            __builtin_amdgcn_s_barrier();
            asm volatile("" ::: "memory");

            const u8* Ab = As[u % 3];
            const u8* Bb = Bs[u % 3];
            l64x2 av[4], bv[4];
#pragma unroll
            for (int m = 0; m < 4; ++m)
                av[m] = *(const l64x2*)(Ab + (wr * 4 + m) * 1024 + lane * 16);
#pragma unroll
            for (int n = 0; n < 4; ++n)
                bv[n] = *(const l64x2*)(Bb + (wc * 4 + n) * 1024 + lane * 16);
#pragma unroll
            for (int m = 0; m < 4; ++m)
#pragma unroll
                for (int n = 0; n < 4; ++n) {
                    acc[m][n] = __builtin_amdgcn_mfma_f32_16x16x32_fp8_fp8(
                        av[m].x, bv[n].x, acc[m][n], 0, 0, 0);
                    acc[m][n] = __builtin_amdgcn_mfma_f32_16x16x32_fp8_fp8(
                        av[m].y, bv[n].y, acc[m][n], 0, 0, 0);
                }

            if (u + 2 < 8) stage((u + 2) % 3, u + 2);
        }

        // epilogue: l2 -> exp-chain (1 exp + 2 sqrt for all 5 bandwidths) -> f32 sum
        const int rowA0 = bi * 128, rowB0 = bj * 128;
        float sqc[4];
#pragma unroll
        for (int n = 0; n < 4; ++n) sqc[n] = sq[rowB0 + wc * 64 + n * 16 + fr];

        float facc = 0.f;
#pragma unroll
        for (int m = 0; m < 4; ++m) {
            float4 s4 = *(const float4*)(sq + rowA0 + wr * 64 + m * 16 + fq * 4);
            float sqr[4] = {s4.x, s4.y, s4.z, s4.w};
#pragma unroll
            for (int n = 0; n < 4; ++n) {
#pragma unroll
                for (int r = 0; r < 4; ++r) {
                    float g = acc[m][n][r];
                    float l2 = fmaxf(sqr[r] + sqc[n] - 2.0f * g, 0.0f);
                    float e = __expf(s2c * l2);
                    float e2 = e * e;
                    float e4 = e2 * e2;
                    float r1, r2;
                    asm("v_sqrt_f32 %0, %1" : "=v"(r1) : "v"(e));
                    asm("v_sqrt_f32 %0, %1" : "=v"(r2) : "v"(r1));
                    facc += e4 + e2 + e + r1 + r2;
                }
            }
        }

        const double wfac = ((bi == bj) ? 1.0 : 2.0) *
                            (((bi < 32) == (bj < 32)) ? 1.0 : -1.0);
        lacc_tot += (double)facc * wfac;
    }

    double v = lacc_tot;
#pragma unroll
    for (int off = 32; off; off >>= 1) v += __shfl_down(v, off);
    __syncthreads();
    if (lane == 0) red[wid] = v;
    __syncthreads();

    if (tid == 0) {
        atomicAdd(accum, red[0] + red[1] + red[2] + red[3]);
        __threadfence();
        u32 done = atomicAdd(counter, 1u);
        if (done == GRID_MMD - 1) {
            double tot = atomicAdd(accum, 0.0);   // device-scope coherent read
            out[0] = (float)(tot / ((double)NS * (double)NS));
        }
    }
}

extern "C" void kernel_launch(void* const* d_in, const int* in_sizes, int n_in,
                              void* d_out, int out_size, void* d_ws, size_t ws_size,
                              hipStream_t stream) {
    const float* src = (const float*)d_in[0];
    const float* tgt = (const float*)d_in[1];
    char* ws = (char*)d_ws;

    const size_t MB4 = 4u * 1024 * 1024;
    u8* Tb        = (u8*)ws;                                  // 4 MiB fp8 fragment-major
    float* sq     = (float*)(ws + MB4);                       // 32 KiB
    float* cp     = (float*)(ws + MB4 + 32 * 1024);           // 512 KiB
    float* scales = (float*)(ws + MB4 + 544 * 1024);          // 32 B (own cacheline)
    double* accum = (double*)(ws + MB4 + 544 * 1024 + 128);   // 8 B
    u32* counter  = (u32*)(ws + MB4 + 544 * 1024 + 192);      // 4 B

    k_prep<<<256, 256, 0, stream>>>(src, tgt, Tb, sq, cp);
    k_band<<<1, 256, 0, stream>>>(sq, cp, scales, accum, counter);
    k_mmd<<<GRID_MMD, 256, 0, stream>>>(Tb, sq, scales, accum, counter, (float*)d_out);
}

// Round 12
// 136.675 us; speedup vs baseline: 1.6166x; 1.0680x over previous
//
#include <hip/hip_runtime.h>
#include <stdint.h>

typedef uint8_t u8;
typedef uint16_t u16;
typedef uint32_t u32;
typedef unsigned long long u64;

#define NS 4096
#define NTOT 8192
#define DIM 512
#define NTILE 2080
#define GRID_MMD 768

typedef __attribute__((ext_vector_type(2))) long l64x2;
typedef __attribute__((ext_vector_type(4))) float f32x4;

__device__ inline void load_lds16(const void* g, void* l) {
    __builtin_amdgcn_global_load_lds((__attribute__((address_space(1))) void*)g,
                                     (__attribute__((address_space(3))) void*)l,
                                     16, 0, 0);
}

// fp8 fragment-major Tb: fragment (rb, kt2) = 16 rows x 64 k in e4m3, contiguous
// 1 KiB at Tb + (rb*8+kt2)*1024. Lane l's 16 B = [sub-step0 8B | sub-step1 8B]:
// byte (l*16 + s*8 + e) = fp8 of row rb*16+(l&15), k = kt2*64 + s*32 + (l>>4)*8 + e.
// One ds_read_b128 per lane feeds TWO mfma_f32_16x16x32_fp8_fp8.

// k_prep: 256 blocks x 256 thr; block = 32 rows. fp8 conversion via LDS transpose
// (contiguous 1 KiB frag stores), per-row sumsq (f32-exact), per-block colsums.
__global__ __launch_bounds__(256) void k_prep(const float* __restrict__ src,
                                              const float* __restrict__ tgt,
                                              u8* __restrict__ Tb,
                                              float* __restrict__ sq,
                                              float* __restrict__ cp) {
    __shared__ u8 xb[2][16][528];       // 528 = 512 + 16B pad
    __shared__ float cs_l[4][DIM];
    const int b = blockIdx.x, tid = threadIdx.x;
    const int w = tid >> 6, lane = tid & 63;
    const int rbl = w >> 1;
    const int i0 = (w & 1) * 8;

    float cs[8];
#pragma unroll
    for (int e = 0; e < 8; ++e) cs[e] = 0.f;

#pragma unroll
    for (int i = 0; i < 8; ++i) {
        const int fr = i0 + i;
        const int r = b * 32 + rbl * 16 + fr;
        const float* rowp = (r < NS) ? (src + (size_t)r * DIM)
                                     : (tgt + (size_t)(r - NS) * DIM);
        float4 v0 = *(const float4*)(rowp + lane * 8);
        float4 v1 = *(const float4*)(rowp + lane * 8 + 4);
        float vx[8] = {v0.x, v0.y, v0.z, v0.w, v1.x, v1.y, v1.z, v1.w};
        float ss = 0.f;
#pragma unroll
        for (int e = 0; e < 8; ++e) { ss += vx[e] * vx[e]; cs[e] += vx[e]; }
        int dlo = 0, dhi = 0;
        dlo = __builtin_amdgcn_cvt_pk_fp8_f32(vx[0], vx[1], dlo, 0);
        dlo = __builtin_amdgcn_cvt_pk_fp8_f32(vx[2], vx[3], dlo, 1);
        dhi = __builtin_amdgcn_cvt_pk_fp8_f32(vx[4], vx[5], dhi, 0);
        dhi = __builtin_amdgcn_cvt_pk_fp8_f32(vx[6], vx[7], dhi, 1);
        *(u32*)&xb[rbl][fr][lane * 8] = (u32)dlo;
        *(u32*)&xb[rbl][fr][lane * 8 + 4] = (u32)dhi;
#pragma unroll
        for (int off = 32; off; off >>= 1) ss += __shfl_down(ss, off);
        if (lane == 0) sq[r] = ss;
    }
#pragma unroll
    for (int e = 0; e < 8; ++e) cs_l[w][lane * 8 + e] = cs[e];
    __syncthreads();

    // frag writes: wave w -> frags w*4..w*4+3 (f: rbl=f>>3, kt2=f&7), coalesced 1 KiB.
    const int row = lane & 15, oct = lane >> 4;
#pragma unroll
    for (int ff = 0; ff < 4; ++ff) {
        const int f = w * 4 + ff;
        const int frbl = f >> 3, kt2 = f & 7;
        u64 a0 = *(const u64*)&xb[frbl][row][kt2 * 64 + oct * 8];
        u64 a1 = *(const u64*)&xb[frbl][row][kt2 * 64 + 32 + oct * 8];
        const int rbg = b * 2 + frbl;
        u8* dst = Tb + (size_t)(rbg * 8 + kt2) * 1024 + lane * 16;
        *(u64*)dst = a0;
        *(u64*)(dst + 8) = a1;
    }

    float a0 = cs_l[0][tid] + cs_l[1][tid] + cs_l[2][tid] + cs_l[3][tid];
    float a1 = cs_l[0][tid + 256] + cs_l[1][tid + 256] + cs_l[2][tid + 256] + cs_l[3][tid + 256];
    cp[(size_t)b * DIM + tid] = a0;
    cp[(size_t)b * DIM + tid + 256] = a1;
}

// k_band: 1 block; bandwidth via sum(l2) = 2*N*sum(sq) - 2*||colsum||^2.
// Writes 5 natural-log scales; zeroes accum + k_mmd counter.
__global__ __launch_bounds__(256) void k_band(const float* __restrict__ sq,
                                              const float* __restrict__ cp,
                                              float* __restrict__ scales,
                                              double* __restrict__ accum,
                                              u32* __restrict__ counter) {
    __shared__ double red[4];
    const int tid = threadIdx.x;
    const int w = tid >> 6, lane = tid & 63;

    double ssq = 0.0;
    for (int i = tid; i < NTOT; i += 256) ssq += (double)sq[i];

    double s2 = 0.0;
#pragma unroll
    for (int cc = 0; cc < 2; ++cc) {
        const int c = tid + cc * 256;
        float b0 = 0.f, b1 = 0.f, b2 = 0.f, b3 = 0.f;
#pragma unroll 8
        for (int k = 0; k < 256; k += 4) {
            b0 += cp[(size_t)(k + 0) * DIM + c];
            b1 += cp[(size_t)(k + 1) * DIM + c];
            b2 += cp[(size_t)(k + 2) * DIM + c];
            b3 += cp[(size_t)(k + 3) * DIM + c];
        }
        double sc = (double)b0 + (double)b1 + (double)b2 + (double)b3;
        s2 += sc * sc;
    }

    auto blkreduce = [&](double v) -> double {
#pragma unroll
        for (int off = 32; off; off >>= 1) v += __shfl_down(v, off);
        __syncthreads();
        if (lane == 0) red[w] = v;
        __syncthreads();
        return red[0] + red[1] + red[2] + red[3];
    };
    double sumsq = blkreduce(ssq);
    double s2t = blkreduce(s2);

    if (tid < 5) {
        const double nn = (double)NTOT;
        double bw = (2.0 * nn * sumsq - 2.0 * s2t) / (nn * nn - nn);
        const double fac[5] = {0.25, 0.5, 1.0, 2.0, 4.0};
        scales[tid] = (float)(-1.0 / (bw * fac[tid] + 1e-8));
    }
    if (tid == 5) *accum = 0.0;
    if (tid == 6) *counter = 0u;
}

// k_mmd: persistent blocks (768 = 3/CU), XCD-chunked triangle, 128x128 fp8 tile,
// 3-buffer depth-2 counted vmcnt, CROSS-TILE pipelining (next tile's first two
// stages issued before/under the epilogue), exp-chain epilogue, counter finish.
__global__ __launch_bounds__(256) void k_mmd(const u8* __restrict__ Tb,
                                             const float* __restrict__ sq,
                                             const float* __restrict__ scales,
                                             double* __restrict__ accum,
                                             u32* __restrict__ counter,
                                             float* __restrict__ out) {
    __shared__ __align__(16) u8 As[3][8192];
    __shared__ __align__(16) u8 Bs[3][8192];
    __shared__ double red[4];

    const int tid = threadIdx.x;
    const int wid = tid >> 6, lane = tid & 63;
    const int wr = wid >> 1, wc = wid & 1;
    const int fr = lane & 15, fq = lane >> 4;
    const float s2c = scales[2];

    const int b = (int)blockIdx.x;
    const int bp = (b & 7) * (GRID_MMD / 8) + (b >> 3);
    const int lo = (int)(((long)bp * NTILE) / GRID_MMD);
    const int hi = (int)(((long)(bp + 1) * NTILE) / GRID_MMD);

    // triangular decomposition of lo (once per block), then incremental walk
    int bi = (int)((sqrtf(8.0f * (float)lo + 1.0f) - 1.0f) * 0.5f);
    while ((bi + 1) * (bi + 2) / 2 <= lo) ++bi;
    while (bi * (bi + 1) / 2 > lo) --bi;
    int bj = lo - bi * (bi + 1) / 2;

    auto stageAB = [&](int tbi, int tbj, int buf, int u) {
#pragma unroll
        for (int q = 0; q < 2; ++q) {
            const int c = wid * 2 + q;
            load_lds16(Tb + (((tbi * 8 + c) * 8 + u) << 10) + lane * 16,
                       &As[buf][c * 1024]);
            load_lds16(Tb + (((tbj * 8 + c) * 8 + u) << 10) + lane * 16,
                       &Bs[buf][c * 1024]);
        }
    };

    double lacc_tot = 0.0;

    stageAB(bi, bj, 0, 0);
    stageAB(bi, bj, 1, 1);

    for (int t = lo; t < hi; ++t) {
        // next tile coords (restage current on last iteration — harmless)
        int nbi = bi, nbj = bj;
        if (t + 1 < hi) {
            nbj = bj + 1;
            if (nbj > nbi) { nbi = bi + 1; nbj = 0; }
        }

        f32x4 acc[4][4];
#pragma unroll
        for (int m = 0; m < 4; ++m)
#pragma unroll
            for (int n = 0; n < 4; ++n) acc[m][n] = (f32x4){0.f, 0.f, 0.f, 0.f};

#pragma unroll
        for (int u = 0; u < 8; ++u) {
            // steady state: 8 outstanding (steps u, u+1); wait the oldest 4.
            if (u == 7) asm volatile("s_waitcnt vmcnt(0)" ::: "memory");
            else        asm volatile("s_waitcnt vmcnt(4)" ::: "memory");
            __builtin_amdgcn_s_barrier();
            asm volatile("" ::: "memory");

            const u8* Ab = As[u % 3];
            const u8* Bb = Bs[u % 3];
            l64x2 av[4], bv[4];
#pragma unroll
            for (int m = 0; m < 4; ++m)
                av[m] = *(const l64x2*)(Ab + (wr * 4 + m) * 1024 + lane * 16);
#pragma unroll
            for (int n = 0; n < 4; ++n)
                bv[n] = *(const l64x2*)(Bb + (wc * 4 + n) * 1024 + lane * 16);
#pragma unroll
            for (int m = 0; m < 4; ++m)
#pragma unroll
                for (int n = 0; n < 4; ++n) {
                    acc[m][n] = __builtin_amdgcn_mfma_f32_16x16x32_fp8_fp8(
                        av[m].x, bv[n].x, acc[m][n], 0, 0, 0);
                    acc[m][n] = __builtin_amdgcn_mfma_f32_16x16x32_fp8_fp8(
                        av[m].y, bv[n].y, acc[m][n], 0, 0, 0);
                }

            if (u + 2 < 8) stageAB(bi, bj, (u + 2) % 3, u + 2);
            if (u == 7) stageAB(nbi, nbj, 0, 0);   // buf0 free: all waves past u=6 reads
        }

        __builtin_amdgcn_s_barrier();              // all waves done compute(7) (buf1)
        asm volatile("" ::: "memory");
        stageAB(nbi, nbj, 1, 1);                   // lands under the epilogue below

        // epilogue: l2 -> exp-chain (1 exp + 2 sqrt for all 5 bandwidths) -> f32 sum
        const int rowA0 = bi * 128, rowB0 = bj * 128;
        float sqc[4];
#pragma unroll
        for (int n = 0; n < 4; ++n) sqc[n] = sq[rowB0 + wc * 64 + n * 16 + fr];

        float facc = 0.f;
#pragma unroll
        for (int m = 0; m < 4; ++m) {
            float4 s4 = *(const float4*)(sq + rowA0 + wr * 64 + m * 16 + fq * 4);
            float sqr[4] = {s4.x, s4.y, s4.z, s4.w};
#pragma unroll
            for (int n = 0; n < 4; ++n) {
#pragma unroll
                for (int r = 0; r < 4; ++r) {
                    float g = acc[m][n][r];
                    float l2 = fmaxf(sqr[r] + sqc[n] - 2.0f * g, 0.0f);
                    float e = __expf(s2c * l2);
                    float e2 = e * e;
                    float e4 = e2 * e2;
                    float r1, r2;
                    asm("v_sqrt_f32 %0, %1" : "=v"(r1) : "v"(e));
                    asm("v_sqrt_f32 %0, %1" : "=v"(r2) : "v"(r1));
                    facc += e4 + e2 + e + r1 + r2;
                }
            }
        }

        const double wfac = ((bi == bj) ? 1.0 : 2.0) *
                            (((bi < 32) == (bj < 32)) ? 1.0 : -1.0);
        lacc_tot += (double)facc * wfac;

        bi = nbi; bj = nbj;
    }

    double v = lacc_tot;
#pragma unroll
    for (int off = 32; off; off >>= 1) v += __shfl_down(v, off);
    __syncthreads();
    if (lane == 0) red[wid] = v;
    __syncthreads();

    if (tid == 0) {
        atomicAdd(accum, red[0] + red[1] + red[2] + red[3]);
        __threadfence();
        u32 done = atomicAdd(counter, 1u);
        if (done == GRID_MMD - 1) {
            double tot = atomicAdd(accum, 0.0);   // device-scope coherent read
            out[0] = (float)(tot / ((double)NS * (double)NS));
        }
    }
}

extern "C" void kernel_launch(void* const* d_in, const int* in_sizes, int n_in,
                              void* d_out, int out_size, void* d_ws, size_t ws_size,
                              hipStream_t stream) {
    const float* src = (const float*)d_in[0];
    const float* tgt = (const float*)d_in[1];
    char* ws = (char*)d_ws;

    const size_t MB4 = 4u * 1024 * 1024;
    u8* Tb        = (u8*)ws;                                  // 4 MiB fp8 fragment-major
    float* sq     = (float*)(ws + MB4);                       // 32 KiB
    float* cp     = (float*)(ws + MB4 + 32 * 1024);           // 512 KiB
    float* scales = (float*)(ws + MB4 + 544 * 1024);          // 32 B (own cacheline)
    double* accum = (double*)(ws + MB4 + 544 * 1024 + 128);   // 8 B
    u32* counter  = (u32*)(ws + MB4 + 544 * 1024 + 192);      // 4 B

    k_prep<<<256, 256, 0, stream>>>(src, tgt, Tb, sq, cp);
    k_band<<<1, 256, 0, stream>>>(sq, cp, scales, accum, counter);
    k_mmd<<<GRID_MMD, 256, 0, stream>>>(Tb, sq, scales, accum, counter, (float*)d_out);
}